// Round 2
// baseline (8276.099 us; speedup 1.0000x reference)
//
#include <hip/hip_runtime.h>
#include <math.h>

#define EPS 1e-5f

constexpr int NCH  = 59;
constexpr int T_   = 300;
constexpr int WIN  = 5;
constexpr int WSIZE= 100;
constexpr int Bb   = 64;
constexpr int NB   = Bb*WIN;     // 320
constexpr int NN   = Bb*NCH;     // 3776
constexpr int EW_N = 216;
constexpr int NE   = EW_N*Bb;    // 13824
constexpr int C1   = 20;
constexpr int C13  = 10;
constexpr int F150 = 150;
constexpr int F100 = 100;
constexpr int HID  = 256;
constexpr int GATES= 1024;
constexpr int NROW = NB*NCH;     // 18880
constexpr float CNT1  = 1888000.0f;   // NB*NCH*WSIZE
constexpr float CNT13 = 2832000.0f;   // NB*NCH*F150

__device__ __forceinline__ float leaky(float v){ return v >= 0.f ? v : 0.01f*v; }
__device__ __forceinline__ float sigm(float v){ return 1.f/(1.f+expf(-v)); }

__global__ __launch_bounds__(256)
void zero_kernel(float* __restrict__ p, int n)
{
    int i = blockIdx.x*256 + threadIdx.x;
    if (i < n) p[i] = 0.f;
}

// ---------------------------------------------------------------------------
// Conv section: one (b,ch) row, all 5 windows of one conv. Each task computes
// 8 positions x 2 channels with an 8-unrolled sliding register window.
// !APPLY: accumulate raw-conv sum/sumsq into lstat_conv[40] (LDS).
//  APPLY: BN + leaky + pair-pool into pooled[win][20][50] (LDS).
// ---------------------------------------------------------------------------
template<int KW, int PAD, int APPLY>
__device__ __forceinline__ void do_conv_section(
    const float* __restrict__ xrow, const float* __restrict__ wt_g,
    float* __restrict__ xp, float* __restrict__ wtp,
    float* __restrict__ lstat_conv,
    const float* __restrict__ sclC, const float* __restrict__ sftC,
    float* __restrict__ pooled)
{
    constexpr int KWP = (KW + 7) & ~7;   // 128 / 64 / 32
    const int tid = threadIdx.x;
    __syncthreads();   // protect xp/wtp/pooled reuse from previous section
    for (int i = tid; i < WIN*240; i += 256){
        int win = i/240, ii = i - win*240;
        int t = ii - PAD;
        xp[i] = (t >= 0 && t < WSIZE) ? xrow[win*50 + t] : 0.f;
    }
    for (int i = tid; i < C1*KWP; i += 256){
        int c = i/KWP, k = i - c*KWP;
        wtp[i] = (k < KW) ? wt_g[c*KW + k] : 0.f;   // zero-padded taps
    }
    __syncthreads();
    for (int task = tid; task < 650; task += 256){   // 5 win * 13 posblk * 10 chpair
        int win = task/130, r = task - win*130;
        int pb = r/10, cp = r - pb*10;
        const float* xw  = &xp[win*240 + pb*8];
        const float* w0p = &wtp[(2*cp)*KWP];
        const float* w1p = &wtp[(2*cp+1)*KWP];
        float xv[16], a0[8], a1[8];
        #pragma unroll
        for (int i=0;i<8;i++){ xv[i]=xw[i]; a0[i]=0.f; a1[i]=0.f; }
        #pragma unroll
        for (int kb=0; kb<KWP/8; kb++){
            #pragma unroll
            for (int i=0;i<8;i++) xv[8+i] = xw[kb*8+8+i];
            #pragma unroll
            for (int j=0;j<8;j++){
                float wv0 = w0p[kb*8+j], wv1 = w1p[kb*8+j];
                #pragma unroll
                for (int p=0;p<8;p++){ a0[p] += wv0*xv[p+j]; a1[p] += wv1*xv[p+j]; }
            }
            #pragma unroll
            for (int i=0;i<8;i++) xv[i] = xv[8+i];
        }
        if (!APPLY){
            float s0=0.f,q0=0.f,s1=0.f,q1=0.f;
            #pragma unroll
            for (int p=0;p<8;p++){
                if (pb*8+p < WSIZE){ s0+=a0[p]; q0+=a0[p]*a0[p]; s1+=a1[p]; q1+=a1[p]*a1[p]; }
            }
            atomicAdd(&lstat_conv[2*cp],      s0);
            atomicAdd(&lstat_conv[C1+2*cp],   q0);
            atomicAdd(&lstat_conv[2*cp+1],    s1);
            atomicAdd(&lstat_conv[C1+2*cp+1], q1);
        } else {
            float sc0 = sclC[2*cp],   sf0 = sftC[2*cp];
            float sc1 = sclC[2*cp+1], sf1 = sftC[2*cp+1];
            #pragma unroll
            for (int p=0;p<8;p+=2){
                int w = pb*8+p;
                if (w < WSIZE){
                    float v00 = leaky(a0[p]*sc0+sf0), v01 = leaky(a0[p+1]*sc0+sf0);
                    pooled[win*1000 + (2*cp)*50 + (w>>1)] = 0.5f*(v00+v01);
                    float v10 = leaky(a1[p]*sc1+sf1), v11 = leaky(a1[p+1]*sc1+sf1);
                    pooled[win*1000 + (2*cp+1)*50 + (w>>1)] = 0.5f*(v10+v11);
                }
            }
        }
    }
}

__device__ __forceinline__ void mix_store(int seg, int b, int hh,
    const float* __restrict__ w13s, const float* __restrict__ pooled,
    float* __restrict__ y13, float* __restrict__ lstat)
{
    __syncthreads();   // pooled complete
    const int tid = threadIdx.x;
    for (int i = tid; i < 2500; i += 256){   // 5 win * 10 o * 50 p
        int win = i/500, r = i - win*500;
        int o = r/50, p = r - o*50;
        float acc = 0.f;
        #pragma unroll
        for (int c=0;c<C1;c++) acc += w13s[o*C1+c]*pooled[win*1000 + c*50 + p];
        y13[(((size_t)(b*WIN+win)*C13 + o)*NCH + hh)*F150 + seg*50 + p] = acc;  // b13 cancels in BN13
        atomicAdd(&lstat[o],      acc);
        atomicAdd(&lstat[C13+o],  acc*acc);
    }
}

template<int APPLY>
__global__ __launch_bounds__(256)
void conv_fused(const float* __restrict__ x,
                const float* __restrict__ w1g, const float* __restrict__ w2g, const float* __restrict__ w3g,
                const float* __restrict__ sclall, const float* __restrict__ sftall,
                const float* __restrict__ w13,
                float* __restrict__ stats1, float* __restrict__ stats13,
                float* __restrict__ y13)
{
    __shared__ float xp[WIN*240];
    __shared__ float wtp[C1*128];
    __shared__ float pooled[APPLY ? WIN*C1*50 : 8];
    __shared__ float w13s[APPLY ? C13*C1 : 8];
    __shared__ float sclS[APPLY ? 60 : 8];
    __shared__ float sftS[APPLY ? 60 : 8];
    __shared__ float lstat[APPLY ? 2*C13 : 120];
    const int bh = blockIdx.x;
    const int b = bh/NCH, hh = bh - b*NCH;
    const int tid = threadIdx.x;
    const float* xrow = x + (size_t)bh*T_;
    if (APPLY){
        for (int i=tid;i<C13*C1;i+=256) w13s[i] = w13[i];
        if (tid < 60){ sclS[tid] = sclall[tid]; sftS[tid] = sftall[tid]; }
        if (tid < 2*C13) lstat[tid] = 0.f;
    } else {
        if (tid < 120) lstat[tid] = 0.f;
    }
    // seg 0: KW=125, seg 1: KW=59, seg 2: KW=31 (barriers inside sections)
    do_conv_section<125,62,APPLY>(xrow, w1g, xp, wtp, &lstat[0],  &sclS[0],  &sftS[0],  pooled);
    if (APPLY) mix_store(0, b, hh, w13s, pooled, y13, lstat);
    do_conv_section<59,29,APPLY>(xrow, w2g, xp, wtp, &lstat[40], &sclS[20], &sftS[20], pooled);
    if (APPLY) mix_store(1, b, hh, w13s, pooled, y13, lstat);
    do_conv_section<31,15,APPLY>(xrow, w3g, xp, wtp, &lstat[80], &sclS[40], &sftS[40], pooled);
    if (APPLY) mix_store(2, b, hh, w13s, pooled, y13, lstat);
    __syncthreads();
    const int st = bh & 63;
    if (!APPLY){
        if (tid < 120) atomicAdd(&stats1[st*120 + tid], lstat[tid]);
    } else {
        if (tid < 2*C13) atomicAdd(&stats13[st*(2*C13) + tid], lstat[tid]);
    }
}

__global__ void finalize_bn1(const float* __restrict__ stats1,
                             const float* __restrict__ g1, const float* __restrict__ be1,
                             const float* __restrict__ g2, const float* __restrict__ be2,
                             const float* __restrict__ g3, const float* __restrict__ be3,
                             float* __restrict__ sclall, float* __restrict__ sftall)
{
    int idx = threadIdx.x;
    if (idx >= 60) return;
    int conv = idx/20, c = idx - conv*20;
    float s=0.f, q=0.f;
    for (int st=0; st<64; st++){
        s += stats1[st*120 + conv*40 + c];
        q += stats1[st*120 + conv*40 + 20 + c];
    }
    float m = s/CNT1, v = q/CNT1 - m*m;
    float rs = rsqrtf(v + EPS);
    const float* g  = conv==0 ? g1  : (conv==1 ? g2  : g3);
    const float* be = conv==0 ? be1 : (conv==1 ? be2 : be3);
    sclall[idx] = rs*g[c];
    sftall[idx] = be[c] - m*rs*g[c];   // conv bias cancels in BN
}

__global__ void finalize_bn13(const float* __restrict__ stats13,
                              const float* __restrict__ g13, const float* __restrict__ be13,
                              float* __restrict__ scl13, float* __restrict__ sft13)
{
    int o = threadIdx.x;
    if (o >= C13) return;
    float s=0.f, q=0.f;
    for (int st=0; st<64; st++){
        s += stats13[st*20 + o];
        q += stats13[st*20 + C13 + o];
    }
    float m = s/CNT13, v = q/CNT13 - m*m;
    float rs = rsqrtf(v + EPS);
    scl13[o] = rs*g13[o];
    sft13[o] = be13[o] - m*rs*g13[o];
}

// -------- BN13 + leaky + sum over channels -> feat (node, win, 150) -----------------------
__global__ __launch_bounds__(256)
void feat_kernel(const float* __restrict__ y13,
                 const float* __restrict__ scl13, const float* __restrict__ sft13,
                 float* __restrict__ feat)
{
    __shared__ float scl[C13], sft[C13];
    int blk = blockIdx.x;
    int n = blk / NCH, hh = blk - n*NCH;
    int b = n / WIN, win = n - b*WIN;
    int tid = threadIdx.x;
    if (tid < C13){ scl[tid] = scl13[tid]; sft[tid] = sft13[tid]; }
    __syncthreads();
    float* fr = feat + ((size_t)(b*NCH+hh)*WIN + win)*F150;
    for (int f = tid; f < F150; f += 256){
        float acc = 0.f;
        #pragma unroll
        for (int o = 0; o < C13; o++){
            float v = y13[((size_t)(n*C13+o)*NCH+hh)*F150 + f];
            acc += leaky(v*scl[o] + sft[o]);
        }
        fr[f] = acc;
    }
}

// -------- h = feat @ gcn_w (18880 x 150 x 100), 8 rows per block ---------------------------
__global__ __launch_bounds__(256)
void gcn_h_kernel(const float* __restrict__ feat, const float* __restrict__ gw,
                  float* __restrict__ h)
{
    __shared__ float fr[8*F150];
    int r0 = blockIdx.x*8;
    int tid = threadIdx.x;
    for (int i = tid; i < 8*F150; i += 256) fr[i] = feat[(size_t)r0*F150 + i];
    __syncthreads();
    for (int idx = tid; idx < 8*F100; idx += 256){
        int rr = idx / F100, j = idx - rr*F100;
        float acc = 0.f;
        const float* f = &fr[rr*F150];
        for (int k = 0; k < F150; k++) acc += f[k]*gw[k*F100 + j];
        h[(size_t)(r0+rr)*F100 + j] = acc;
    }
}

__global__ void deg_kernel(const int* __restrict__ ei, const float* __restrict__ ew,
                           float* __restrict__ deg)
{
    int e = blockIdx.x*blockDim.x + threadIdx.x;
    if (e >= NE) return;
    int c = ei[NE + e];
    float w = ew[e % EW_N]; w = w > 0.f ? w : 0.f;
    atomicAdd(&deg[c], w);
}

__global__ void dinv_kernel(float* __restrict__ deg)
{
    int i = blockIdx.x*blockDim.x + threadIdx.x;
    if (i < NN) deg[i] = rsqrtf(deg[i] + 1.0f);
}

__global__ __launch_bounds__(64)
void agg_kernel(const int* __restrict__ ei, const float* __restrict__ ew,
                const float* __restrict__ dinv, const float* __restrict__ h,
                float* __restrict__ agg)
{
    int e = blockIdx.x;
    int r = ei[e], c = ei[NE + e];
    float w = ew[e % EW_N]; w = w > 0.f ? w : 0.f;
    float nrm = dinv[r]*w*dinv[c];
    const float* hr = h + (size_t)r*(WIN*F100);
    float* ac = agg + (size_t)c*(WIN*F100);
    for (int i = threadIdx.x; i < WIN*F100; i += 64)
        atomicAdd(&ac[i], hr[i]*nrm);
}

__global__ __launch_bounds__(256)
void bn2_stats_kernel(const float* __restrict__ h, const float* __restrict__ dinv,
                      float* __restrict__ agg, float* __restrict__ s2sum, float* __restrict__ s2sq)
{
    int tid = threadIdx.x;
    int c0 = tid, c1 = tid + 256;
    float s0=0.f,q0=0.f,s1=0.f,q1=0.f;
    for (int rr = 0; rr < NCH; rr++){
        int node = blockIdx.x*NCH + rr;
        float d = dinv[node]; float d2 = d*d;
        const float* hr = h + (size_t)node*(WIN*F100);
        float* ar = agg + (size_t)node*(WIN*F100);
        float v0 = ar[c0] + hr[c0]*d2;          // gcn_b cancels in BN2
        ar[c0] = v0; s0 += v0; q0 += v0*v0;
        if (c1 < WIN*F100){
            float v1 = ar[c1] + hr[c1]*d2;
            ar[c1] = v1; s1 += v1; q1 += v1*v1;
        }
    }
    atomicAdd(&s2sum[c0], s0); atomicAdd(&s2sq[c0], q0);
    if (c1 < WIN*F100){ atomicAdd(&s2sum[c1], s1); atomicAdd(&s2sq[c1], q1); }
}

__global__ void bn2_fin_kernel(const float* __restrict__ s2sum, const float* __restrict__ s2sq,
                               const float* __restrict__ g2, const float* __restrict__ b2,
                               float* __restrict__ scl2, float* __restrict__ sft2)
{
    int c = blockIdx.x*blockDim.x + threadIdx.x;
    if (c >= WIN*F100) return;
    int f = c % F100;
    float m = s2sum[c]/(float)NN;
    float v = s2sq[c]/(float)NN - m*m;
    float rs = rsqrtf(v + EPS);
    scl2[c] = rs*g2[f];
    sft2[c] = b2[f] - m*rs*g2[f];
}

// -------- BN2 apply + (10,1,59,2) conv + leaky + pool -> seq (64,5,490) --------------------
__global__ __launch_bounds__(256)
void zconv_kernel(const float* __restrict__ agg,
                  const float* __restrict__ scl2, const float* __restrict__ sft2,
                  const float* __restrict__ w11, const float* __restrict__ b11,
                  float* __restrict__ seq)
{
    __shared__ float z[NCH*WSIZE];
    __shared__ float ws[C13*NCH*2];
    __shared__ float sc[WSIZE], sf[WSIZE];
    int n = blockIdx.x;
    int b = n / WIN, win = n - b*WIN;
    int tid = threadIdx.x;
    if (tid < WSIZE){ sc[tid] = scl2[win*F100 + tid]; sf[tid] = sft2[win*F100 + tid]; }
    for (int i = tid; i < C13*NCH*2; i += 256) ws[i] = w11[i];
    __syncthreads();
    for (int i = tid; i < NCH*WSIZE; i += 256){
        int ch = i / WSIZE, t = i - ch*WSIZE;
        int node = b*NCH + ch;
        float v = agg[(size_t)node*(WIN*F100) + win*F100 + t];
        z[i] = v*sc[t] + sf[t];
    }
    __syncthreads();
    float* sq = seq + (size_t)n*490;
    for (int idx = tid; idx < C13*49; idx += 256){
        int o = idx / 49, p = idx - o*49;
        float ve = b11[o], vo = b11[o];
        const float* wo = &ws[o*NCH*2];
        for (int ch = 0; ch < NCH; ch++){
            float z0 = z[ch*WSIZE + 2*p];
            float z1 = z[ch*WSIZE + 2*p + 1];
            float z2 = z[ch*WSIZE + 2*p + 2];
            float w0 = wo[ch*2], w1 = wo[ch*2 + 1];
            ve += w0*z0 + w1*z1;
            vo += w0*z1 + w1*z2;
        }
        sq[o*49 + p] = 0.5f*(leaky(ve) + leaky(vo));
    }
}

__global__ void transpose_kernel(const float* __restrict__ src, float* __restrict__ dst, int R, int C)
{
    int idx = blockIdx.x*blockDim.x + threadIdx.x;
    if (idx >= R*C) return;
    int r = idx % R, c = idx / R;
    dst[idx] = src[(size_t)r*C + c];
}

// -------- 2-layer LSTM + attention, one block per batch element ---------------------------
__global__ __launch_bounds__(256)
void lstm_attn_kernel(const float* __restrict__ seq,
                      const float* __restrict__ wih0T, const float* __restrict__ whh0T,
                      const float* __restrict__ bih0, const float* __restrict__ bhh0,
                      const float* __restrict__ wih1T, const float* __restrict__ whh1T,
                      const float* __restrict__ bih1, const float* __restrict__ bhh1,
                      float* __restrict__ out)
{
    __shared__ float xs[490];
    __shared__ float hbuf[HID];
    __shared__ float gates[GATES];
    __shared__ float bb[GATES];
    __shared__ float out1[WIN*HID];
    __shared__ float out2[WIN*HID];
    __shared__ float red[5*4];
    __shared__ float aw[5];
    int b = blockIdx.x;
    int tid = threadIdx.x;
    int j0 = tid*4;

    // ---- layer 0 ----
    for (int i = tid; i < GATES; i += 256) bb[i] = bih0[i] + bhh0[i];
    hbuf[tid] = 0.f;
    float c_reg = 0.f;
    __syncthreads();
    for (int t = 0; t < WIN; t++){
        for (int i = tid; i < 490; i += 256) xs[i] = seq[(size_t)(b*WIN + t)*490 + i];
        __syncthreads();
        float4 acc = *(const float4*)&bb[j0];
        for (int k = 0; k < 490; k++){
            float xv = xs[k];
            float4 w = *(const float4*)&wih0T[(size_t)k*GATES + j0];
            acc.x += w.x*xv; acc.y += w.y*xv; acc.z += w.z*xv; acc.w += w.w*xv;
        }
        for (int k = 0; k < HID; k++){
            float hv = hbuf[k];
            float4 w = *(const float4*)&whh0T[(size_t)k*GATES + j0];
            acc.x += w.x*hv; acc.y += w.y*hv; acc.z += w.z*hv; acc.w += w.w*hv;
        }
        *(float4*)&gates[j0] = acc;
        __syncthreads();
        float gi = gates[tid], gf = gates[HID+tid], gg = gates[2*HID+tid], go = gates[3*HID+tid];
        c_reg = sigm(gf)*c_reg + sigm(gi)*tanhf(gg);
        float hn = sigm(go)*tanhf(c_reg);
        __syncthreads();
        hbuf[tid] = hn;
        out1[t*HID + tid] = hn;
    }
    __syncthreads();
    // ---- layer 1 ----
    for (int i = tid; i < GATES; i += 256) bb[i] = bih1[i] + bhh1[i];
    hbuf[tid] = 0.f;
    c_reg = 0.f;
    for (int t = 0; t < WIN; t++){
        __syncthreads();
        float4 acc = *(const float4*)&bb[j0];
        const float* x1 = &out1[t*HID];
        for (int k = 0; k < HID; k++){
            float xv = x1[k];
            float4 w = *(const float4*)&wih1T[(size_t)k*GATES + j0];
            acc.x += w.x*xv; acc.y += w.y*xv; acc.z += w.z*xv; acc.w += w.w*xv;
        }
        for (int k = 0; k < HID; k++){
            float hv = hbuf[k];
            float4 w = *(const float4*)&whh1T[(size_t)k*GATES + j0];
            acc.x += w.x*hv; acc.y += w.y*hv; acc.z += w.z*hv; acc.w += w.w*hv;
        }
        *(float4*)&gates[j0] = acc;
        __syncthreads();
        float gi = gates[tid], gf = gates[HID+tid], gg = gates[2*HID+tid], go = gates[3*HID+tid];
        c_reg = sigm(gf)*c_reg + sigm(gi)*tanhf(gg);
        float hn = sigm(go)*tanhf(c_reg);
        __syncthreads();
        hbuf[tid] = hn;
        out2[t*HID + tid] = hn;
    }
    __syncthreads();
    // ---- attention ----
    float hl = out2[4*HID + tid];
    int wave = tid >> 6, lane = tid & 63;
    for (int t = 0; t < 5; t++){
        float p = out2[t*HID + tid]*hl;
        for (int off = 32; off > 0; off >>= 1) p += __shfl_down(p, off);
        if (lane == 0) red[t*4 + wave] = p;
    }
    __syncthreads();
    if (tid == 0){
        float s[5], mx = -1e30f;
        for (int t = 0; t < 5; t++){ s[t] = red[t*4]+red[t*4+1]+red[t*4+2]+red[t*4+3]; mx = fmaxf(mx, s[t]); }
        float den = 0.f;
        for (int t = 0; t < 5; t++){ s[t] = expf(s[t]-mx); den += s[t]; }
        for (int t = 0; t < 5; t++) aw[t] = s[t]/den;
    }
    __syncthreads();
    float o = 0.f;
    for (int t = 0; t < 5; t++) o += aw[t]*out2[t*HID + tid];
    out[(size_t)b*HID + tid] = o;
}

extern "C" void kernel_launch(void* const* d_in, const int* in_sizes, int n_in,
                              void* d_out, int out_size, void* d_ws, size_t ws_size,
                              hipStream_t stream)
{
    const float* x     = (const float*)d_in[0];
    const float* w1    = (const float*)d_in[1];
    const float* g1    = (const float*)d_in[3];
    const float* be1   = (const float*)d_in[4];
    const float* w2    = (const float*)d_in[5];
    const float* g2    = (const float*)d_in[7];
    const float* be2   = (const float*)d_in[8];
    const float* w3    = (const float*)d_in[9];
    const float* g3    = (const float*)d_in[11];
    const float* be3   = (const float*)d_in[12];
    const float* w13   = (const float*)d_in[13];
    const float* g13   = (const float*)d_in[15];
    const float* be13  = (const float*)d_in[16];
    const float* gcn_w = (const float*)d_in[17];
    const float* edge_w= (const float*)d_in[19];
    const float* bn2g  = (const float*)d_in[20];
    const float* bn2b  = (const float*)d_in[21];
    const float* w11   = (const float*)d_in[22];
    const float* b11   = (const float*)d_in[23];
    const float* wih0  = (const float*)d_in[24];
    const float* whh0  = (const float*)d_in[25];
    const float* bih0  = (const float*)d_in[26];
    const float* bhh0  = (const float*)d_in[27];
    const float* wih1  = (const float*)d_in[28];
    const float* whh1  = (const float*)d_in[29];
    const float* bih1  = (const float*)d_in[30];
    const float* bhh1  = (const float*)d_in[31];
    const int*   ei    = (const int*)d_in[32];
    float* out = (float*)d_out;
    float* wsf = (float*)d_ws;
    (void)in_sizes; (void)n_in; (void)out_size; (void)ws_size;

    size_t off = 0;
    auto alloc = [&](size_t n){ size_t o = off; off += (n + 63) & ~(size_t)63; return o; };
    size_t Y13  = alloc((size_t)NB*C13*NCH*F150);    // 28,320,000 (113 MB)
    size_t FEAT = alloc((size_t)NN*WIN*F150);        //  2,832,000
    size_t HB   = alloc((size_t)NN*WIN*F100);        //  1,888,000
    size_t AGG  = alloc((size_t)NN*WIN*F100);        //  1,888,000  [zeroed]
    size_t DEG  = alloc(NN);                         //  [zeroed]
    size_t ST1  = alloc(64*120);                     //  [zeroed]
    size_t ST13 = alloc(64*20);                      //  [zeroed]
    size_t BN2S = alloc(1000);                       //  [zeroed]
    size_t SCLA = alloc(64);                         // end of zero region
    size_t SFTA = alloc(64);
    size_t SC13 = alloc(16);
    size_t SF13 = alloc(16);
    size_t SCL2 = alloc(1024);                       // 500 scale + 500 shift (at +500)
    size_t WT0I = alloc((size_t)490*1024);
    size_t WT0H = alloc((size_t)256*1024);
    size_t WT1I = alloc((size_t)256*1024);
    size_t WT1H = alloc((size_t)256*1024);
    size_t SEQ  = alloc((size_t)Bb*WIN*490);
    // total ~36.4M floats ~= 145.5 MB

    float* y13   = wsf + Y13;
    float* feat  = wsf + FEAT;
    float* hbuf  = wsf + HB;
    float* agg   = wsf + AGG;
    float* dinv  = wsf + DEG;
    float* st1   = wsf + ST1;
    float* st13  = wsf + ST13;
    float* bn2s  = wsf + BN2S;
    float* sclA  = wsf + SCLA;
    float* sftA  = wsf + SFTA;
    float* sc13  = wsf + SC13;
    float* sf13  = wsf + SF13;
    float* scl2  = wsf + SCL2;
    float* wT0i  = wsf + WT0I;
    float* wT0h  = wsf + WT0H;
    float* wT1i  = wsf + WT1I;
    float* wT1h  = wsf + WT1H;
    float* seqb  = wsf + SEQ;

    int nzero = (int)(SCLA - AGG);
    zero_kernel<<<(nzero+255)/256,256,0,stream>>>(wsf + AGG, nzero);

    {
        int n0 = 1024*490;
        transpose_kernel<<<(n0+255)/256,256,0,stream>>>(wih0, wT0i, 1024, 490);
        int n1 = 1024*256;
        transpose_kernel<<<(n1+255)/256,256,0,stream>>>(whh0, wT0h, 1024, 256);
        transpose_kernel<<<(n1+255)/256,256,0,stream>>>(wih1, wT1i, 1024, 256);
        transpose_kernel<<<(n1+255)/256,256,0,stream>>>(whh1, wT1h, 1024, 256);
    }

    conv_fused<0><<<NN,256,0,stream>>>(x, w1, w2, w3, sclA, sftA, w13, st1, st13, y13);
    finalize_bn1<<<1,64,0,stream>>>(st1, g1, be1, g2, be2, g3, be3, sclA, sftA);
    conv_fused<1><<<NN,256,0,stream>>>(x, w1, w2, w3, sclA, sftA, w13, st1, st13, y13);
    finalize_bn13<<<1,16,0,stream>>>(st13, g13, be13, sc13, sf13);

    feat_kernel<<<NROW,256,0,stream>>>(y13, sc13, sf13, feat);
    gcn_h_kernel<<<NROW/8,256,0,stream>>>(feat, gcn_w, hbuf);

    deg_kernel<<<(NE+255)/256,256,0,stream>>>(ei, edge_w, dinv);
    dinv_kernel<<<(NN+255)/256,256,0,stream>>>(dinv);
    agg_kernel<<<NE,64,0,stream>>>(ei, edge_w, dinv, hbuf, agg);
    bn2_stats_kernel<<<Bb,256,0,stream>>>(hbuf, dinv, agg, bn2s, bn2s+500);
    bn2_fin_kernel<<<2,256,0,stream>>>(bn2s, bn2s+500, bn2g, bn2b, scl2, scl2+500);

    zconv_kernel<<<NB,256,0,stream>>>(agg, scl2, scl2+500, w11, b11, seqb);

    lstm_attn_kernel<<<Bb,256,0,stream>>>(seqb, wT0i, wT0h, bih0, bhh0,
                                          wT1i, wT1h, bih1, bhh1, out);
}

// Round 4
// 1639.284 us; speedup vs baseline: 5.0486x; 5.0486x over previous
//
#include <hip/hip_runtime.h>
#include <math.h>

#define EPS 1e-5f

constexpr int NCH  = 59;
constexpr int T_   = 300;
constexpr int WIN  = 5;
constexpr int WSIZE= 100;
constexpr int Bb   = 64;
constexpr int NB   = Bb*WIN;     // 320
constexpr int NN   = Bb*NCH;     // 3776
constexpr int EW_N = 216;
constexpr int NE   = EW_N*Bb;    // 13824
constexpr int C1   = 20;
constexpr int C13  = 10;
constexpr int F150 = 150;
constexpr int F100 = 100;
constexpr int HID  = 256;
constexpr int GATES= 1024;
constexpr int NROW = NB*NCH;     // 18880
constexpr int NWINROW = NROW;    // blocks: (b,hh,win) = 18880
constexpr float CNT1  = 1888000.0f;   // NB*NCH*WSIZE
constexpr float CNT13 = 2832000.0f;   // NB*NCH*F150

__device__ __forceinline__ float leaky(float v){ return v >= 0.f ? v : 0.01f*v; }
__device__ __forceinline__ float sigm(float v){ return 1.f/(1.f+expf(-v)); }

__global__ __launch_bounds__(256)
void zero_kernel(float* __restrict__ p, int n)
{
    int i = blockIdx.x*256 + threadIdx.x;
    if (i < n) p[i] = 0.f;
}

// ---------------------------------------------------------------------------
// 1-D conv, one (b,hh,win) window per block, one conv size per launch.
// 250 active threads: task = pb*10 + cp  (pb: 25 blocks of 4 positions,
// cp: 10 channel pairs). Per-thread: 8 accumulators + 12-reg sliding window.
// APPLY=0: accumulate per-channel sum/sumsq -> striped stats1.
// APPLY=1: BN+leaky+pool -> LDS pooled[20][50], then 1x1 mix (20->10) ->
//          y13 seg + striped stats13.
// ---------------------------------------------------------------------------
template<int KW, int PAD, int CIDX, int APPLY>
__global__ __launch_bounds__(256)
void conv1d_kernel(const float* __restrict__ x, const float* __restrict__ wt_g,
                   const float* __restrict__ sclall, const float* __restrict__ sftall,
                   const float* __restrict__ w13,
                   float* __restrict__ stats1, float* __restrict__ stats13,
                   float* __restrict__ y13)
{
    constexpr int KWP = (KW + 7) & ~7;     // 128 / 64 / 32
    __shared__ float xp[240];
    __shared__ float wt2[KWP*C1];          // [k][c], zero-padded taps
    __shared__ float pooled[APPLY ? C1*50 : 1];
    __shared__ float w13s[APPLY ? C13*C1 : 1];
    __shared__ float sclS[APPLY ? C1 : 1];
    __shared__ float sftS[APPLY ? C1 : 1];
    __shared__ float lstat[APPLY ? 2*C13 : 2*C1];

    const int blk = blockIdx.x;
    const int row = blk / WIN;             // b*NCH + hh
    const int win = blk - row*WIN;
    const int b   = row / NCH, hh = row - b*NCH;
    const int tid = threadIdx.x;
    const float* xrow = x + (size_t)row*T_ + win*50;

    for (int i = tid; i < 240; i += 256){
        int t = i - PAD;
        xp[i] = (t >= 0 && t < WSIZE) ? xrow[t] : 0.f;
    }
    for (int i = tid; i < KWP*C1; i += 256){
        int k = i / C1, c = i - k*C1;
        wt2[i] = (k < KW) ? wt_g[c*KW + k] : 0.f;
    }
    if (APPLY){
        for (int i = tid; i < C13*C1; i += 256) w13s[i] = w13[i];
        if (tid < C1){ sclS[tid] = sclall[CIDX*C1 + tid]; sftS[tid] = sftall[CIDX*C1 + tid]; }
        if (tid < 2*C13) lstat[tid] = 0.f;
    } else {
        if (tid < 2*C1) lstat[tid] = 0.f;
    }
    __syncthreads();

    const int pb = tid / 10, cp = tid - pb*10;
    const bool active = (tid < 250);
    float a[8];                            // a[p*2+ch], p=0..3, ch in pair
    if (active){
        const float* xw = &xp[pb*4];
        #pragma unroll
        for (int i = 0; i < 8; i++) a[i] = 0.f;
        float xv[12];
        #pragma unroll
        for (int i = 0; i < 4; i++) xv[i] = xw[i];
        for (int kb = 0; kb < KWP/8; kb++){
            const int k0 = kb*8;
            #pragma unroll
            for (int i = 0; i < 8; i++) xv[4+i] = xw[k0 + 4 + i];
            #pragma unroll
            for (int j = 0; j < 8; j++){
                float2 wv = *(const float2*)&wt2[(k0 + j)*C1 + 2*cp];
                #pragma unroll
                for (int p = 0; p < 4; p++){
                    a[p*2+0] += wv.x * xv[j+p];
                    a[p*2+1] += wv.y * xv[j+p];
                }
            }
            #pragma unroll
            for (int i = 0; i < 4; i++) xv[i] = xv[8+i];
        }
        if (!APPLY){
            float s0=0.f,q0=0.f,s1=0.f,q1=0.f;
            #pragma unroll
            for (int p = 0; p < 4; p++){
                s0 += a[p*2];   q0 += a[p*2]*a[p*2];
                s1 += a[p*2+1]; q1 += a[p*2+1]*a[p*2+1];
            }
            atomicAdd(&lstat[2*cp],        s0);
            atomicAdd(&lstat[C1 + 2*cp],   q0);
            atomicAdd(&lstat[2*cp+1],      s1);
            atomicAdd(&lstat[C1 + 2*cp+1], q1);
        } else {
            float sc0 = sclS[2*cp],   sf0 = sftS[2*cp];
            float sc1 = sclS[2*cp+1], sf1 = sftS[2*cp+1];
            float v00 = leaky(a[0]*sc0+sf0), v01 = leaky(a[2]*sc0+sf0);
            float v02 = leaky(a[4]*sc0+sf0), v03 = leaky(a[6]*sc0+sf0);
            pooled[(2*cp)*50 + pb*2    ] = 0.5f*(v00+v01);
            pooled[(2*cp)*50 + pb*2 + 1] = 0.5f*(v02+v03);
            float v10 = leaky(a[1]*sc1+sf1), v11 = leaky(a[3]*sc1+sf1);
            float v12 = leaky(a[5]*sc1+sf1), v13 = leaky(a[7]*sc1+sf1);
            pooled[(2*cp+1)*50 + pb*2    ] = 0.5f*(v10+v11);
            pooled[(2*cp+1)*50 + pb*2 + 1] = 0.5f*(v12+v13);
        }
    }
    __syncthreads();
    if (APPLY){
        for (int i = tid; i < C13*50; i += 256){
            int o = i/50, p = i - o*50;
            float acc = 0.f;
            #pragma unroll
            for (int c = 0; c < C1; c++) acc += w13s[o*C1 + c]*pooled[c*50 + p];
            y13[(((size_t)(b*WIN + win)*C13 + o)*NCH + hh)*F150 + CIDX*50 + p] = acc; // b13 cancels in BN13
            atomicAdd(&lstat[o],        acc);
            atomicAdd(&lstat[C13 + o],  acc*acc);
        }
        __syncthreads();
        const int st = blk & 63;
        if (tid < 2*C13) atomicAdd(&stats13[st*(2*C13) + tid], lstat[tid]);
    } else {
        const int st = blk & 63;
        if (tid < 2*C1) atomicAdd(&stats1[st*120 + CIDX*40 + tid], lstat[tid]);
    }
}

__global__ void finalize_bn1(const float* __restrict__ stats1,
                             const float* __restrict__ g1, const float* __restrict__ be1,
                             const float* __restrict__ g2, const float* __restrict__ be2,
                             const float* __restrict__ g3, const float* __restrict__ be3,
                             float* __restrict__ sclall, float* __restrict__ sftall)
{
    int idx = threadIdx.x;
    if (idx >= 60) return;
    int conv = idx/20, c = idx - conv*20;
    float s=0.f, q=0.f;
    for (int st=0; st<64; st++){
        s += stats1[st*120 + conv*40 + c];
        q += stats1[st*120 + conv*40 + 20 + c];
    }
    float m = s/CNT1, v = q/CNT1 - m*m;
    float rs = rsqrtf(v + EPS);
    const float* g  = conv==0 ? g1  : (conv==1 ? g2  : g3);
    const float* be = conv==0 ? be1 : (conv==1 ? be2 : be3);
    sclall[idx] = rs*g[c];
    sftall[idx] = be[c] - m*rs*g[c];   // conv bias cancels in BN
}

__global__ void finalize_bn13(const float* __restrict__ stats13,
                              const float* __restrict__ g13, const float* __restrict__ be13,
                              float* __restrict__ scl13, float* __restrict__ sft13)
{
    int o = threadIdx.x;
    if (o >= C13) return;
    float s=0.f, q=0.f;
    for (int st=0; st<64; st++){
        s += stats13[st*20 + o];
        q += stats13[st*20 + C13 + o];
    }
    float m = s/CNT13, v = q/CNT13 - m*m;
    float rs = rsqrtf(v + EPS);
    scl13[o] = rs*g13[o];
    sft13[o] = be13[o] - m*rs*g13[o];
}

// -------- BN13 + leaky + sum over channels -> feat (node, win, 150) -----------------------
__global__ __launch_bounds__(256)
void feat_kernel(const float* __restrict__ y13,
                 const float* __restrict__ scl13, const float* __restrict__ sft13,
                 float* __restrict__ feat)
{
    __shared__ float scl[C13], sft[C13];
    int blk = blockIdx.x;
    int n = blk / NCH, hh = blk - n*NCH;
    int b = n / WIN, win = n - b*WIN;
    int tid = threadIdx.x;
    if (tid < C13){ scl[tid] = scl13[tid]; sft[tid] = sft13[tid]; }
    __syncthreads();
    float* fr = feat + ((size_t)(b*NCH+hh)*WIN + win)*F150;
    for (int f = tid; f < F150; f += 256){
        float acc = 0.f;
        #pragma unroll
        for (int o = 0; o < C13; o++){
            float v = y13[((size_t)(n*C13+o)*NCH+hh)*F150 + f];
            acc += leaky(v*scl[o] + sft[o]);
        }
        fr[f] = acc;
    }
}

// -------- h = feat @ gcn_w (18880 x 150 x 100), 8 rows per block ---------------------------
__global__ __launch_bounds__(256)
void gcn_h_kernel(const float* __restrict__ feat, const float* __restrict__ gw,
                  float* __restrict__ h)
{
    __shared__ float fr[8*F150];
    int r0 = blockIdx.x*8;
    int tid = threadIdx.x;
    for (int i = tid; i < 8*F150; i += 256) fr[i] = feat[(size_t)r0*F150 + i];
    __syncthreads();
    for (int idx = tid; idx < 8*F100; idx += 256){
        int rr = idx / F100, j = idx - rr*F100;
        float acc = 0.f;
        const float* f = &fr[rr*F150];
        for (int k = 0; k < F150; k++) acc += f[k]*gw[k*F100 + j];
        h[(size_t)(r0+rr)*F100 + j] = acc;
    }
}

__global__ void deg_kernel(const int* __restrict__ ei, const float* __restrict__ ew,
                           float* __restrict__ deg)
{
    int e = blockIdx.x*blockDim.x + threadIdx.x;
    if (e >= NE) return;
    int c = ei[NE + e];
    float w = ew[e % EW_N]; w = w > 0.f ? w : 0.f;
    atomicAdd(&deg[c], w);
}

__global__ void dinv_kernel(float* __restrict__ deg)
{
    int i = blockIdx.x*blockDim.x + threadIdx.x;
    if (i < NN) deg[i] = rsqrtf(deg[i] + 1.0f);
}

__global__ __launch_bounds__(64)
void agg_kernel(const int* __restrict__ ei, const float* __restrict__ ew,
                const float* __restrict__ dinv, const float* __restrict__ h,
                float* __restrict__ agg)
{
    int e = blockIdx.x;
    int r = ei[e], c = ei[NE + e];
    float w = ew[e % EW_N]; w = w > 0.f ? w : 0.f;
    float nrm = dinv[r]*w*dinv[c];
    const float* hr = h + (size_t)r*(WIN*F100);
    float* ac = agg + (size_t)c*(WIN*F100);
    for (int i = threadIdx.x; i < WIN*F100; i += 64)
        atomicAdd(&ac[i], hr[i]*nrm);
}

__global__ __launch_bounds__(256)
void bn2_stats_kernel(const float* __restrict__ h, const float* __restrict__ dinv,
                      float* __restrict__ agg, float* __restrict__ s2sum, float* __restrict__ s2sq)
{
    int tid = threadIdx.x;
    int c0 = tid, c1 = tid + 256;
    float s0=0.f,q0=0.f,s1=0.f,q1=0.f;
    for (int rr = 0; rr < NCH; rr++){
        int node = blockIdx.x*NCH + rr;
        float d = dinv[node]; float d2 = d*d;
        const float* hr = h + (size_t)node*(WIN*F100);
        float* ar = agg + (size_t)node*(WIN*F100);
        float v0 = ar[c0] + hr[c0]*d2;          // gcn_b cancels in BN2
        ar[c0] = v0; s0 += v0; q0 += v0*v0;
        if (c1 < WIN*F100){
            float v1 = ar[c1] + hr[c1]*d2;
            ar[c1] = v1; s1 += v1; q1 += v1*v1;
        }
    }
    atomicAdd(&s2sum[c0], s0); atomicAdd(&s2sq[c0], q0);
    if (c1 < WIN*F100){ atomicAdd(&s2sum[c1], s1); atomicAdd(&s2sq[c1], q1); }
}

__global__ void bn2_fin_kernel(const float* __restrict__ s2sum, const float* __restrict__ s2sq,
                               const float* __restrict__ g2, const float* __restrict__ b2,
                               float* __restrict__ scl2, float* __restrict__ sft2)
{
    int c = blockIdx.x*blockDim.x + threadIdx.x;
    if (c >= WIN*F100) return;
    int f = c % F100;
    float m = s2sum[c]/(float)NN;
    float v = s2sq[c]/(float)NN - m*m;
    float rs = rsqrtf(v + EPS);
    scl2[c] = rs*g2[f];
    sft2[c] = b2[f] - m*rs*g2[f];
}

// -------- BN2 apply + (10,1,59,2) conv + leaky + pool -> seq (64,5,490) --------------------
__global__ __launch_bounds__(256)
void zconv_kernel(const float* __restrict__ agg,
                  const float* __restrict__ scl2, const float* __restrict__ sft2,
                  const float* __restrict__ w11, const float* __restrict__ b11,
                  float* __restrict__ seq)
{
    __shared__ float z[NCH*WSIZE];
    __shared__ float ws[C13*NCH*2];
    __shared__ float sc[WSIZE], sf[WSIZE];
    int n = blockIdx.x;
    int b = n / WIN, win = n - b*WIN;
    int tid = threadIdx.x;
    if (tid < WSIZE){ sc[tid] = scl2[win*F100 + tid]; sf[tid] = sft2[win*F100 + tid]; }
    for (int i = tid; i < C13*NCH*2; i += 256) ws[i] = w11[i];
    __syncthreads();
    for (int i = tid; i < NCH*WSIZE; i += 256){
        int ch = i / WSIZE, t = i - ch*WSIZE;
        int node = b*NCH + ch;
        float v = agg[(size_t)node*(WIN*F100) + win*F100 + t];
        z[i] = v*sc[t] + sf[t];
    }
    __syncthreads();
    float* sq = seq + (size_t)n*490;
    for (int idx = tid; idx < C13*49; idx += 256){
        int o = idx / 49, p = idx - o*49;
        float ve = b11[o], vo = b11[o];
        const float* wo = &ws[o*NCH*2];
        for (int ch = 0; ch < NCH; ch++){
            float z0 = z[ch*WSIZE + 2*p];
            float z1 = z[ch*WSIZE + 2*p + 1];
            float z2 = z[ch*WSIZE + 2*p + 2];
            float w0 = wo[ch*2], w1 = wo[ch*2 + 1];
            ve += w0*z0 + w1*z1;
            vo += w0*z1 + w1*z2;
        }
        sq[o*49 + p] = 0.5f*(leaky(ve) + leaky(vo));
    }
}

__global__ void transpose_kernel(const float* __restrict__ src, float* __restrict__ dst, int R, int C)
{
    int idx = blockIdx.x*blockDim.x + threadIdx.x;
    if (idx >= R*C) return;
    int r = idx % R, c = idx / R;
    dst[idx] = src[(size_t)r*C + c];
}

// -------- 2-layer LSTM + attention, one block per batch element ---------------------------
__global__ __launch_bounds__(256)
void lstm_attn_kernel(const float* __restrict__ seq,
                      const float* __restrict__ wih0T, const float* __restrict__ whh0T,
                      const float* __restrict__ bih0, const float* __restrict__ bhh0,
                      const float* __restrict__ wih1T, const float* __restrict__ whh1T,
                      const float* __restrict__ bih1, const float* __restrict__ bhh1,
                      float* __restrict__ out)
{
    __shared__ float xs[490];
    __shared__ float hbuf[HID];
    __shared__ float gates[GATES];
    __shared__ float bb[GATES];
    __shared__ float out1[WIN*HID];
    __shared__ float out2[WIN*HID];
    __shared__ float red[5*4];
    __shared__ float aw[5];
    int b = blockIdx.x;
    int tid = threadIdx.x;
    int j0 = tid*4;

    // ---- layer 0 ----
    for (int i = tid; i < GATES; i += 256) bb[i] = bih0[i] + bhh0[i];
    hbuf[tid] = 0.f;
    float c_reg = 0.f;
    __syncthreads();
    for (int t = 0; t < WIN; t++){
        for (int i = tid; i < 490; i += 256) xs[i] = seq[(size_t)(b*WIN + t)*490 + i];
        __syncthreads();
        float4 acc = *(const float4*)&bb[j0];
        for (int k = 0; k < 490; k++){
            float xv = xs[k];
            float4 w = *(const float4*)&wih0T[(size_t)k*GATES + j0];
            acc.x += w.x*xv; acc.y += w.y*xv; acc.z += w.z*xv; acc.w += w.w*xv;
        }
        for (int k = 0; k < HID; k++){
            float hv = hbuf[k];
            float4 w = *(const float4*)&whh0T[(size_t)k*GATES + j0];
            acc.x += w.x*hv; acc.y += w.y*hv; acc.z += w.z*hv; acc.w += w.w*hv;
        }
        *(float4*)&gates[j0] = acc;
        __syncthreads();
        float gi = gates[tid], gf = gates[HID+tid], gg = gates[2*HID+tid], go = gates[3*HID+tid];
        c_reg = sigm(gf)*c_reg + sigm(gi)*tanhf(gg);
        float hn = sigm(go)*tanhf(c_reg);
        __syncthreads();
        hbuf[tid] = hn;
        out1[t*HID + tid] = hn;
    }
    __syncthreads();
    // ---- layer 1 ----
    for (int i = tid; i < GATES; i += 256) bb[i] = bih1[i] + bhh1[i];
    hbuf[tid] = 0.f;
    c_reg = 0.f;
    for (int t = 0; t < WIN; t++){
        __syncthreads();
        float4 acc = *(const float4*)&bb[j0];
        const float* x1 = &out1[t*HID];
        for (int k = 0; k < HID; k++){
            float xv = x1[k];
            float4 w = *(const float4*)&wih1T[(size_t)k*GATES + j0];
            acc.x += w.x*xv; acc.y += w.y*xv; acc.z += w.z*xv; acc.w += w.w*xv;
        }
        for (int k = 0; k < HID; k++){
            float hv = hbuf[k];
            float4 w = *(const float4*)&whh1T[(size_t)k*GATES + j0];
            acc.x += w.x*hv; acc.y += w.y*hv; acc.z += w.z*hv; acc.w += w.w*hv;
        }
        *(float4*)&gates[j0] = acc;
        __syncthreads();
        float gi = gates[tid], gf = gates[HID+tid], gg = gates[2*HID+tid], go = gates[3*HID+tid];
        c_reg = sigm(gf)*c_reg + sigm(gi)*tanhf(gg);
        float hn = sigm(go)*tanhf(c_reg);
        __syncthreads();
        hbuf[tid] = hn;
        out2[t*HID + tid] = hn;
    }
    __syncthreads();
    // ---- attention ----
    float hl = out2[4*HID + tid];
    int wave = tid >> 6, lane = tid & 63;
    for (int t = 0; t < 5; t++){
        float p = out2[t*HID + tid]*hl;
        for (int off = 32; off > 0; off >>= 1) p += __shfl_down(p, off);
        if (lane == 0) red[t*4 + wave] = p;
    }
    __syncthreads();
    if (tid == 0){
        float s[5], mx = -1e30f;
        for (int t = 0; t < 5; t++){ s[t] = red[t*4]+red[t*4+1]+red[t*4+2]+red[t*4+3]; mx = fmaxf(mx, s[t]); }
        float den = 0.f;
        for (int t = 0; t < 5; t++){ s[t] = expf(s[t]-mx); den += s[t]; }
        for (int t = 0; t < 5; t++) aw[t] = s[t]/den;
    }
    __syncthreads();
    float o = 0.f;
    for (int t = 0; t < 5; t++) o += aw[t]*out2[t*HID + tid];
    out[(size_t)b*HID + tid] = o;
}

extern "C" void kernel_launch(void* const* d_in, const int* in_sizes, int n_in,
                              void* d_out, int out_size, void* d_ws, size_t ws_size,
                              hipStream_t stream)
{
    const float* x     = (const float*)d_in[0];
    const float* w1    = (const float*)d_in[1];
    const float* g1    = (const float*)d_in[3];
    const float* be1   = (const float*)d_in[4];
    const float* w2    = (const float*)d_in[5];
    const float* g2    = (const float*)d_in[7];
    const float* be2   = (const float*)d_in[8];
    const float* w3    = (const float*)d_in[9];
    const float* g3    = (const float*)d_in[11];
    const float* be3   = (const float*)d_in[12];
    const float* w13   = (const float*)d_in[13];
    const float* g13   = (const float*)d_in[15];
    const float* be13  = (const float*)d_in[16];
    const float* gcn_w = (const float*)d_in[17];
    const float* edge_w= (const float*)d_in[19];
    const float* bn2g  = (const float*)d_in[20];
    const float* bn2b  = (const float*)d_in[21];
    const float* w11   = (const float*)d_in[22];
    const float* b11   = (const float*)d_in[23];
    const float* wih0  = (const float*)d_in[24];
    const float* whh0  = (const float*)d_in[25];
    const float* bih0  = (const float*)d_in[26];
    const float* bhh0  = (const float*)d_in[27];
    const float* wih1  = (const float*)d_in[28];
    const float* whh1  = (const float*)d_in[29];
    const float* bih1  = (const float*)d_in[30];
    const float* bhh1  = (const float*)d_in[31];
    const int*   ei    = (const int*)d_in[32];
    float* out = (float*)d_out;
    float* wsf = (float*)d_ws;
    (void)in_sizes; (void)n_in; (void)out_size; (void)ws_size;

    size_t off = 0;
    auto alloc = [&](size_t n){ size_t o = off; off += (n + 63) & ~(size_t)63; return o; };
    size_t Y13  = alloc((size_t)NB*C13*NCH*F150);    // 28,320,000 (113 MB)
    size_t FEAT = alloc((size_t)NN*WIN*F150);
    size_t HB   = alloc((size_t)NN*WIN*F100);
    size_t AGG  = alloc((size_t)NN*WIN*F100);        // [zeroed]
    size_t DEG  = alloc(NN);                         // [zeroed]
    size_t ST1  = alloc(64*120);                     // [zeroed]
    size_t ST13 = alloc(64*20);                      // [zeroed]
    size_t BN2S = alloc(1000);                       // [zeroed]
    size_t SCLA = alloc(64);                         // end of zero region
    size_t SFTA = alloc(64);
    size_t SC13 = alloc(16);
    size_t SF13 = alloc(16);
    size_t SCL2 = alloc(1024);
    size_t WT0I = alloc((size_t)490*1024);
    size_t WT0H = alloc((size_t)256*1024);
    size_t WT1I = alloc((size_t)256*1024);
    size_t WT1H = alloc((size_t)256*1024);
    size_t SEQ  = alloc((size_t)Bb*WIN*490);

    float* y13   = wsf + Y13;
    float* feat  = wsf + FEAT;
    float* hbuf  = wsf + HB;
    float* agg   = wsf + AGG;
    float* dinv  = wsf + DEG;
    float* st1   = wsf + ST1;
    float* st13  = wsf + ST13;
    float* bn2s  = wsf + BN2S;
    float* sclA  = wsf + SCLA;
    float* sftA  = wsf + SFTA;
    float* sc13  = wsf + SC13;
    float* sf13  = wsf + SF13;
    float* scl2  = wsf + SCL2;
    float* wT0i  = wsf + WT0I;
    float* wT0h  = wsf + WT0H;
    float* wT1i  = wsf + WT1I;
    float* wT1h  = wsf + WT1H;
    float* seqb  = wsf + SEQ;

    int nzero = (int)(SCLA - AGG);
    zero_kernel<<<(nzero+255)/256,256,0,stream>>>(wsf + AGG, nzero);

    {
        int n0 = 1024*490;
        transpose_kernel<<<(n0+255)/256,256,0,stream>>>(wih0, wT0i, 1024, 490);
        int n1 = 1024*256;
        transpose_kernel<<<(n1+255)/256,256,0,stream>>>(whh0, wT0h, 1024, 256);
        transpose_kernel<<<(n1+255)/256,256,0,stream>>>(wih1, wT1i, 1024, 256);
        transpose_kernel<<<(n1+255)/256,256,0,stream>>>(whh1, wT1h, 1024, 256);
    }

    // pass A: stats
    conv1d_kernel<125,62,0,0><<<NWINROW,256,0,stream>>>(x, w1, sclA, sftA, w13, st1, st13, y13);
    conv1d_kernel< 59,29,1,0><<<NWINROW,256,0,stream>>>(x, w2, sclA, sftA, w13, st1, st13, y13);
    conv1d_kernel< 31,15,2,0><<<NWINROW,256,0,stream>>>(x, w3, sclA, sftA, w13, st1, st13, y13);
    finalize_bn1<<<1,64,0,stream>>>(st1, g1, be1, g2, be2, g3, be3, sclA, sftA);
    // pass B: apply + mix
    conv1d_kernel<125,62,0,1><<<NWINROW,256,0,stream>>>(x, w1, sclA, sftA, w13, st1, st13, y13);
    conv1d_kernel< 59,29,1,1><<<NWINROW,256,0,stream>>>(x, w2, sclA, sftA, w13, st1, st13, y13);
    conv1d_kernel< 31,15,2,1><<<NWINROW,256,0,stream>>>(x, w3, sclA, sftA, w13, st1, st13, y13);
    finalize_bn13<<<1,16,0,stream>>>(st13, g13, be13, sc13, sf13);

    feat_kernel<<<NROW,256,0,stream>>>(y13, sc13, sf13, feat);
    gcn_h_kernel<<<NROW/8,256,0,stream>>>(feat, gcn_w, hbuf);

    deg_kernel<<<(NE+255)/256,256,0,stream>>>(ei, edge_w, dinv);
    dinv_kernel<<<(NN+255)/256,256,0,stream>>>(dinv);
    agg_kernel<<<NE,64,0,stream>>>(ei, edge_w, dinv, hbuf, agg);
    bn2_stats_kernel<<<Bb,256,0,stream>>>(hbuf, dinv, agg, bn2s, bn2s+500);
    bn2_fin_kernel<<<2,256,0,stream>>>(bn2s, bn2s+500, bn2g, bn2b, scl2, scl2+500);

    zconv_kernel<<<NB,256,0,stream>>>(agg, scl2, scl2+500, w11, b11, seqb);

    lstm_attn_kernel<<<Bb,256,0,stream>>>(seqb, wT0i, wT0h, bih0, bhh0,
                                          wT1i, wT1h, bih1, bhh1, out);
}

// Round 5
// 1081.337 us; speedup vs baseline: 7.6536x; 1.5160x over previous
//
#include <hip/hip_runtime.h>
#include <math.h>

#define EPS 1e-5f

constexpr int NCH  = 59;
constexpr int T_   = 300;
constexpr int WIN  = 5;
constexpr int WSIZE= 100;
constexpr int Bb   = 64;
constexpr int NB   = Bb*WIN;     // 320
constexpr int NN   = Bb*NCH;     // 3776
constexpr int EW_N = 216;
constexpr int NE   = EW_N*Bb;    // 13824
constexpr int C1   = 20;
constexpr int C13  = 10;
constexpr int F150 = 150;
constexpr int F100 = 100;
constexpr int HID  = 256;
constexpr int GATES= 1024;
constexpr int NROW = NB*NCH;     // 18880
constexpr float CNT1  = 1888000.0f;   // NB*NCH*WSIZE
constexpr float CNT13 = 2832000.0f;   // NB*NCH*F150

__device__ __forceinline__ float leaky(float v){ return v >= 0.f ? v : 0.01f*v; }
__device__ __forceinline__ float sigm(float v){ return 1.f/(1.f+expf(-v)); }

__global__ __launch_bounds__(256)
void zero_kernel(float* __restrict__ p, int n)
{
    int i = blockIdx.x*256 + threadIdx.x;
    if (i < n) p[i] = 0.f;
}

// ---------------------------------------------------------------------------
// 1-D conv, one (b,hh) ROW per block (all 5 windows), one conv size per launch.
// 250 active threads: thread = (win, u) -> conv positions 2u, 2u+1.
// Weights read via wave-uniform scalar loads (SGPR broadcast, no LDS issue);
// x via one sliding ds_read_b32 per tap (stride-2 lanes = free 2-way alias).
// Per-thread state: a0[20], a1[20] accumulators - no spill, no task loop.
// APPLY=0: per-channel sum/sumsq -> shuffle-reduce -> striped stats1.
// APPLY=1: BN+leaky+pool in-register, 1x1 mix (20->10) in-register (SGPR w13)
//          -> y13 seg + shuffle-reduced striped stats13.
// ---------------------------------------------------------------------------
template<int KW, int PAD, int CIDX, int APPLY>
__global__ __launch_bounds__(256)
void conv1d_kernel(const float* __restrict__ x, const float* __restrict__ wt_g,
                   const float* __restrict__ sclall, const float* __restrict__ sftall,
                   const float* __restrict__ w13,
                   float* __restrict__ stats1, float* __restrict__ stats13,
                   float* __restrict__ y13)
{
    __shared__ float xp[WIN*240];
    __shared__ float lstat[2*C1];

    const int row = blockIdx.x;            // b*NCH + hh
    const int b   = row / NCH, hh = row - b*NCH;
    const int tid = threadIdx.x;
    const float* xrow = x + (size_t)row*T_;

    for (int i = tid; i < WIN*240; i += 256){
        int win = i/240, ii = i - win*240;
        int t = ii - PAD;
        xp[i] = (t >= 0 && t < WSIZE) ? xrow[win*50 + t] : 0.f;
    }
    if (tid < 2*C1) lstat[tid] = 0.f;
    __syncthreads();

    const bool active = (tid < 250);
    const int win = tid / 50, u = tid - win*50;   // win<5, u<50 when active

    float a0[C1], a1[C1];
    #pragma unroll
    for (int c = 0; c < C1; c++){ a0[c] = 0.f; a1[c] = 0.f; }

    if (active){
        const float* xw = &xp[win*240 + 2*u];
        float xa = xw[0];
        #pragma unroll 2
        for (int k = 0; k < KW; k++){
            float xb = xw[k+1];
            #pragma unroll
            for (int c = 0; c < C1; c++){
                float wv = wt_g[c*KW + k];      // wave-uniform -> s_load
                a0[c] += wv*xa;
                a1[c] += wv*xb;
            }
            xa = xb;
        }
    }

    if (!APPLY){
        #pragma unroll
        for (int c = 0; c < C1; c++){
            float s = a0[c] + a1[c];
            float q = a0[c]*a0[c] + a1[c]*a1[c];
            for (int off = 32; off; off >>= 1){
                s += __shfl_down(s, off, 64);
                q += __shfl_down(q, off, 64);
            }
            if ((tid & 63) == 0){
                atomicAdd(&lstat[c],      s);
                atomicAdd(&lstat[C1 + c], q);
            }
        }
        __syncthreads();
        const int st = row & 63;
        if (tid < 2*C1) atomicAdd(&stats1[st*120 + CIDX*40 + tid], lstat[tid]);
    } else {
        float y[C13];
        if (active){
            float pooled[C1];
            #pragma unroll
            for (int c = 0; c < C1; c++){
                float sc = sclall[CIDX*C1 + c];   // uniform -> s_load
                float sf = sftall[CIDX*C1 + c];
                pooled[c] = 0.5f*(leaky(a0[c]*sc + sf) + leaky(a1[c]*sc + sf));
            }
            #pragma unroll
            for (int o = 0; o < C13; o++){
                float acc = 0.f;
                #pragma unroll
                for (int c = 0; c < C1; c++) acc += w13[o*C1 + c]*pooled[c];  // uniform
                y[o] = acc;                       // b13 cancels in BN13
            }
            const int n = b*WIN + win;
            #pragma unroll
            for (int o = 0; o < C13; o++)
                y13[(((size_t)n*C13 + o)*NCH + hh)*F150 + CIDX*50 + u] = y[o];
        } else {
            #pragma unroll
            for (int o = 0; o < C13; o++) y[o] = 0.f;
        }
        #pragma unroll
        for (int o = 0; o < C13; o++){
            float s = y[o], q = y[o]*y[o];
            for (int off = 32; off; off >>= 1){
                s += __shfl_down(s, off, 64);
                q += __shfl_down(q, off, 64);
            }
            if ((tid & 63) == 0){
                atomicAdd(&lstat[o],       s);
                atomicAdd(&lstat[C13 + o], q);
            }
        }
        __syncthreads();
        const int st = row & 63;
        if (tid < 2*C13) atomicAdd(&stats13[st*(2*C13) + tid], lstat[tid]);
    }
}

__global__ void finalize_bn1(const float* __restrict__ stats1,
                             const float* __restrict__ g1, const float* __restrict__ be1,
                             const float* __restrict__ g2, const float* __restrict__ be2,
                             const float* __restrict__ g3, const float* __restrict__ be3,
                             float* __restrict__ sclall, float* __restrict__ sftall)
{
    int idx = threadIdx.x;
    if (idx >= 60) return;
    int conv = idx/20, c = idx - conv*20;
    float s=0.f, q=0.f;
    for (int st=0; st<64; st++){
        s += stats1[st*120 + conv*40 + c];
        q += stats1[st*120 + conv*40 + 20 + c];
    }
    float m = s/CNT1, v = q/CNT1 - m*m;
    float rs = rsqrtf(v + EPS);
    const float* g  = conv==0 ? g1  : (conv==1 ? g2  : g3);
    const float* be = conv==0 ? be1 : (conv==1 ? be2 : be3);
    sclall[idx] = rs*g[c];
    sftall[idx] = be[c] - m*rs*g[c];   // conv bias cancels in BN
}

__global__ void finalize_bn13(const float* __restrict__ stats13,
                              const float* __restrict__ g13, const float* __restrict__ be13,
                              float* __restrict__ scl13, float* __restrict__ sft13)
{
    int o = threadIdx.x;
    if (o >= C13) return;
    float s=0.f, q=0.f;
    for (int st=0; st<64; st++){
        s += stats13[st*20 + o];
        q += stats13[st*20 + C13 + o];
    }
    float m = s/CNT13, v = q/CNT13 - m*m;
    float rs = rsqrtf(v + EPS);
    scl13[o] = rs*g13[o];
    sft13[o] = be13[o] - m*rs*g13[o];
}

// -------- BN13 + leaky + sum over channels -> feat (node, win, 150) -----------------------
__global__ __launch_bounds__(256)
void feat_kernel(const float* __restrict__ y13,
                 const float* __restrict__ scl13, const float* __restrict__ sft13,
                 float* __restrict__ feat)
{
    __shared__ float scl[C13], sft[C13];
    int blk = blockIdx.x;
    int n = blk / NCH, hh = blk - n*NCH;
    int b = n / WIN, win = n - b*WIN;
    int tid = threadIdx.x;
    if (tid < C13){ scl[tid] = scl13[tid]; sft[tid] = sft13[tid]; }
    __syncthreads();
    float* fr = feat + ((size_t)(b*NCH+hh)*WIN + win)*F150;
    for (int f = tid; f < F150; f += 256){
        float acc = 0.f;
        #pragma unroll
        for (int o = 0; o < C13; o++){
            float v = y13[((size_t)(n*C13+o)*NCH+hh)*F150 + f];
            acc += leaky(v*scl[o] + sft[o]);
        }
        fr[f] = acc;
    }
}

// -------- h = feat @ gcn_w (18880 x 150 x 100), 8 rows per block ---------------------------
__global__ __launch_bounds__(256)
void gcn_h_kernel(const float* __restrict__ feat, const float* __restrict__ gw,
                  float* __restrict__ h)
{
    __shared__ float fr[8*F150];
    int r0 = blockIdx.x*8;
    int tid = threadIdx.x;
    for (int i = tid; i < 8*F150; i += 256) fr[i] = feat[(size_t)r0*F150 + i];
    __syncthreads();
    for (int idx = tid; idx < 8*F100; idx += 256){
        int rr = idx / F100, j = idx - rr*F100;
        float acc = 0.f;
        const float* f = &fr[rr*F150];
        for (int k = 0; k < F150; k++) acc += f[k]*gw[k*F100 + j];
        h[(size_t)(r0+rr)*F100 + j] = acc;
    }
}

__global__ void deg_kernel(const int* __restrict__ ei, const float* __restrict__ ew,
                           float* __restrict__ deg)
{
    int e = blockIdx.x*blockDim.x + threadIdx.x;
    if (e >= NE) return;
    int c = ei[NE + e];
    float w = ew[e % EW_N]; w = w > 0.f ? w : 0.f;
    atomicAdd(&deg[c], w);
}

__global__ void dinv_kernel(float* __restrict__ deg)
{
    int i = blockIdx.x*blockDim.x + threadIdx.x;
    if (i < NN) deg[i] = rsqrtf(deg[i] + 1.0f);
}

__global__ __launch_bounds__(64)
void agg_kernel(const int* __restrict__ ei, const float* __restrict__ ew,
                const float* __restrict__ dinv, const float* __restrict__ h,
                float* __restrict__ agg)
{
    int e = blockIdx.x;
    int r = ei[e], c = ei[NE + e];
    float w = ew[e % EW_N]; w = w > 0.f ? w : 0.f;
    float nrm = dinv[r]*w*dinv[c];
    const float* hr = h + (size_t)r*(WIN*F100);
    float* ac = agg + (size_t)c*(WIN*F100);
    for (int i = threadIdx.x; i < WIN*F100; i += 64)
        atomicAdd(&ac[i], hr[i]*nrm);
}

__global__ __launch_bounds__(256)
void bn2_stats_kernel(const float* __restrict__ h, const float* __restrict__ dinv,
                      float* __restrict__ agg, float* __restrict__ s2sum, float* __restrict__ s2sq)
{
    int tid = threadIdx.x;
    int c0 = tid, c1 = tid + 256;
    float s0=0.f,q0=0.f,s1=0.f,q1=0.f;
    for (int rr = 0; rr < NCH; rr++){
        int node = blockIdx.x*NCH + rr;
        float d = dinv[node]; float d2 = d*d;
        const float* hr = h + (size_t)node*(WIN*F100);
        float* ar = agg + (size_t)node*(WIN*F100);
        float v0 = ar[c0] + hr[c0]*d2;          // gcn_b cancels in BN2
        ar[c0] = v0; s0 += v0; q0 += v0*v0;
        if (c1 < WIN*F100){
            float v1 = ar[c1] + hr[c1]*d2;
            ar[c1] = v1; s1 += v1; q1 += v1*v1;
        }
    }
    atomicAdd(&s2sum[c0], s0); atomicAdd(&s2sq[c0], q0);
    if (c1 < WIN*F100){ atomicAdd(&s2sum[c1], s1); atomicAdd(&s2sq[c1], q1); }
}

__global__ void bn2_fin_kernel(const float* __restrict__ s2sum, const float* __restrict__ s2sq,
                               const float* __restrict__ g2, const float* __restrict__ b2,
                               float* __restrict__ scl2, float* __restrict__ sft2)
{
    int c = blockIdx.x*blockDim.x + threadIdx.x;
    if (c >= WIN*F100) return;
    int f = c % F100;
    float m = s2sum[c]/(float)NN;
    float v = s2sq[c]/(float)NN - m*m;
    float rs = rsqrtf(v + EPS);
    scl2[c] = rs*g2[f];
    sft2[c] = b2[f] - m*rs*g2[f];
}

// -------- BN2 apply + (10,1,59,2) conv + leaky + pool -> seq (64,5,490) --------------------
__global__ __launch_bounds__(256)
void zconv_kernel(const float* __restrict__ agg,
                  const float* __restrict__ scl2, const float* __restrict__ sft2,
                  const float* __restrict__ w11, const float* __restrict__ b11,
                  float* __restrict__ seq)
{
    __shared__ float z[NCH*WSIZE];
    __shared__ float ws[C13*NCH*2];
    __shared__ float sc[WSIZE], sf[WSIZE];
    int n = blockIdx.x;
    int b = n / WIN, win = n - b*WIN;
    int tid = threadIdx.x;
    if (tid < WSIZE){ sc[tid] = scl2[win*F100 + tid]; sf[tid] = sft2[win*F100 + tid]; }
    for (int i = tid; i < C13*NCH*2; i += 256) ws[i] = w11[i];
    __syncthreads();
    for (int i = tid; i < NCH*WSIZE; i += 256){
        int ch = i / WSIZE, t = i - ch*WSIZE;
        int node = b*NCH + ch;
        float v = agg[(size_t)node*(WIN*F100) + win*F100 + t];
        z[i] = v*sc[t] + sf[t];
    }
    __syncthreads();
    float* sq = seq + (size_t)n*490;
    for (int idx = tid; idx < C13*49; idx += 256){
        int o = idx / 49, p = idx - o*49;
        float ve = b11[o], vo = b11[o];
        const float* wo = &ws[o*NCH*2];
        for (int ch = 0; ch < NCH; ch++){
            float z0 = z[ch*WSIZE + 2*p];
            float z1 = z[ch*WSIZE + 2*p + 1];
            float z2 = z[ch*WSIZE + 2*p + 2];
            float w0 = wo[ch*2], w1 = wo[ch*2 + 1];
            ve += w0*z0 + w1*z1;
            vo += w0*z1 + w1*z2;
        }
        sq[o*49 + p] = 0.5f*(leaky(ve) + leaky(vo));
    }
}

__global__ void transpose_kernel(const float* __restrict__ src, float* __restrict__ dst, int R, int C)
{
    int idx = blockIdx.x*blockDim.x + threadIdx.x;
    if (idx >= R*C) return;
    int r = idx % R, c = idx / R;
    dst[idx] = src[(size_t)r*C + c];
}

// -------- 2-layer LSTM + attention, one block per batch element ---------------------------
__global__ __launch_bounds__(256)
void lstm_attn_kernel(const float* __restrict__ seq,
                      const float* __restrict__ wih0T, const float* __restrict__ whh0T,
                      const float* __restrict__ bih0, const float* __restrict__ bhh0,
                      const float* __restrict__ wih1T, const float* __restrict__ whh1T,
                      const float* __restrict__ bih1, const float* __restrict__ bhh1,
                      float* __restrict__ out)
{
    __shared__ float xs[490];
    __shared__ float hbuf[HID];
    __shared__ float gates[GATES];
    __shared__ float bb[GATES];
    __shared__ float out1[WIN*HID];
    __shared__ float out2[WIN*HID];
    __shared__ float red[5*4];
    __shared__ float aw[5];
    int b = blockIdx.x;
    int tid = threadIdx.x;
    int j0 = tid*4;

    // ---- layer 0 ----
    for (int i = tid; i < GATES; i += 256) bb[i] = bih0[i] + bhh0[i];
    hbuf[tid] = 0.f;
    float c_reg = 0.f;
    __syncthreads();
    for (int t = 0; t < WIN; t++){
        for (int i = tid; i < 490; i += 256) xs[i] = seq[(size_t)(b*WIN + t)*490 + i];
        __syncthreads();
        float4 acc = *(const float4*)&bb[j0];
        for (int k = 0; k < 490; k++){
            float xv = xs[k];
            float4 w = *(const float4*)&wih0T[(size_t)k*GATES + j0];
            acc.x += w.x*xv; acc.y += w.y*xv; acc.z += w.z*xv; acc.w += w.w*xv;
        }
        for (int k = 0; k < HID; k++){
            float hv = hbuf[k];
            float4 w = *(const float4*)&whh0T[(size_t)k*GATES + j0];
            acc.x += w.x*hv; acc.y += w.y*hv; acc.z += w.z*hv; acc.w += w.w*hv;
        }
        *(float4*)&gates[j0] = acc;
        __syncthreads();
        float gi = gates[tid], gf = gates[HID+tid], gg = gates[2*HID+tid], go = gates[3*HID+tid];
        c_reg = sigm(gf)*c_reg + sigm(gi)*tanhf(gg);
        float hn = sigm(go)*tanhf(c_reg);
        __syncthreads();
        hbuf[tid] = hn;
        out1[t*HID + tid] = hn;
    }
    __syncthreads();
    // ---- layer 1 ----
    for (int i = tid; i < GATES; i += 256) bb[i] = bih1[i] + bhh1[i];
    hbuf[tid] = 0.f;
    c_reg = 0.f;
    for (int t = 0; t < WIN; t++){
        __syncthreads();
        float4 acc = *(const float4*)&bb[j0];
        const float* x1 = &out1[t*HID];
        for (int k = 0; k < HID; k++){
            float xv = x1[k];
            float4 w = *(const float4*)&wih1T[(size_t)k*GATES + j0];
            acc.x += w.x*xv; acc.y += w.y*xv; acc.z += w.z*xv; acc.w += w.w*xv;
        }
        for (int k = 0; k < HID; k++){
            float hv = hbuf[k];
            float4 w = *(const float4*)&whh1T[(size_t)k*GATES + j0];
            acc.x += w.x*hv; acc.y += w.y*hv; acc.z += w.z*hv; acc.w += w.w*hv;
        }
        *(float4*)&gates[j0] = acc;
        __syncthreads();
        float gi = gates[tid], gf = gates[HID+tid], gg = gates[2*HID+tid], go = gates[3*HID+tid];
        c_reg = sigm(gf)*c_reg + sigm(gi)*tanhf(gg);
        float hn = sigm(go)*tanhf(c_reg);
        __syncthreads();
        hbuf[tid] = hn;
        out2[t*HID + tid] = hn;
    }
    __syncthreads();
    // ---- attention ----
    float hl = out2[4*HID + tid];
    int wave = tid >> 6, lane = tid & 63;
    for (int t = 0; t < 5; t++){
        float p = out2[t*HID + tid]*hl;
        for (int off = 32; off > 0; off >>= 1) p += __shfl_down(p, off);
        if (lane == 0) red[t*4 + wave] = p;
    }
    __syncthreads();
    if (tid == 0){
        float s[5], mx = -1e30f;
        for (int t = 0; t < 5; t++){ s[t] = red[t*4]+red[t*4+1]+red[t*4+2]+red[t*4+3]; mx = fmaxf(mx, s[t]); }
        float den = 0.f;
        for (int t = 0; t < 5; t++){ s[t] = expf(s[t]-mx); den += s[t]; }
        for (int t = 0; t < 5; t++) aw[t] = s[t]/den;
    }
    __syncthreads();
    float o = 0.f;
    for (int t = 0; t < 5; t++) o += aw[t]*out2[t*HID + tid];
    out[(size_t)b*HID + tid] = o;
}

extern "C" void kernel_launch(void* const* d_in, const int* in_sizes, int n_in,
                              void* d_out, int out_size, void* d_ws, size_t ws_size,
                              hipStream_t stream)
{
    const float* x     = (const float*)d_in[0];
    const float* w1    = (const float*)d_in[1];
    const float* g1    = (const float*)d_in[3];
    const float* be1   = (const float*)d_in[4];
    const float* w2    = (const float*)d_in[5];
    const float* g2    = (const float*)d_in[7];
    const float* be2   = (const float*)d_in[8];
    const float* w3    = (const float*)d_in[9];
    const float* g3    = (const float*)d_in[11];
    const float* be3   = (const float*)d_in[12];
    const float* w13   = (const float*)d_in[13];
    const float* g13   = (const float*)d_in[15];
    const float* be13  = (const float*)d_in[16];
    const float* gcn_w = (const float*)d_in[17];
    const float* edge_w= (const float*)d_in[19];
    const float* bn2g  = (const float*)d_in[20];
    const float* bn2b  = (const float*)d_in[21];
    const float* w11   = (const float*)d_in[22];
    const float* b11   = (const float*)d_in[23];
    const float* wih0  = (const float*)d_in[24];
    const float* whh0  = (const float*)d_in[25];
    const float* bih0  = (const float*)d_in[26];
    const float* bhh0  = (const float*)d_in[27];
    const float* wih1  = (const float*)d_in[28];
    const float* whh1  = (const float*)d_in[29];
    const float* bih1  = (const float*)d_in[30];
    const float* bhh1  = (const float*)d_in[31];
    const int*   ei    = (const int*)d_in[32];
    float* out = (float*)d_out;
    float* wsf = (float*)d_ws;
    (void)in_sizes; (void)n_in; (void)out_size; (void)ws_size;

    size_t off = 0;
    auto alloc = [&](size_t n){ size_t o = off; off += (n + 63) & ~(size_t)63; return o; };
    size_t Y13  = alloc((size_t)NB*C13*NCH*F150);    // 28,320,000 (113 MB)
    size_t FEAT = alloc((size_t)NN*WIN*F150);
    size_t HB   = alloc((size_t)NN*WIN*F100);
    size_t AGG  = alloc((size_t)NN*WIN*F100);        // [zeroed]
    size_t DEG  = alloc(NN);                         // [zeroed]
    size_t ST1  = alloc(64*120);                     // [zeroed]
    size_t ST13 = alloc(64*20);                      // [zeroed]
    size_t BN2S = alloc(1000);                       // [zeroed]
    size_t SCLA = alloc(64);                         // end of zero region
    size_t SFTA = alloc(64);
    size_t SC13 = alloc(16);
    size_t SF13 = alloc(16);
    size_t SCL2 = alloc(1024);
    size_t WT0I = alloc((size_t)490*1024);
    size_t WT0H = alloc((size_t)256*1024);
    size_t WT1I = alloc((size_t)256*1024);
    size_t WT1H = alloc((size_t)256*1024);
    size_t SEQ  = alloc((size_t)Bb*WIN*490);

    float* y13   = wsf + Y13;
    float* feat  = wsf + FEAT;
    float* hbuf  = wsf + HB;
    float* agg   = wsf + AGG;
    float* dinv  = wsf + DEG;
    float* st1   = wsf + ST1;
    float* st13  = wsf + ST13;
    float* bn2s  = wsf + BN2S;
    float* sclA  = wsf + SCLA;
    float* sftA  = wsf + SFTA;
    float* sc13  = wsf + SC13;
    float* sf13  = wsf + SF13;
    float* scl2  = wsf + SCL2;
    float* wT0i  = wsf + WT0I;
    float* wT0h  = wsf + WT0H;
    float* wT1i  = wsf + WT1I;
    float* wT1h  = wsf + WT1H;
    float* seqb  = wsf + SEQ;

    int nzero = (int)(SCLA - AGG);
    zero_kernel<<<(nzero+255)/256,256,0,stream>>>(wsf + AGG, nzero);

    {
        int n0 = 1024*490;
        transpose_kernel<<<(n0+255)/256,256,0,stream>>>(wih0, wT0i, 1024, 490);
        int n1 = 1024*256;
        transpose_kernel<<<(n1+255)/256,256,0,stream>>>(whh0, wT0h, 1024, 256);
        transpose_kernel<<<(n1+255)/256,256,0,stream>>>(wih1, wT1i, 1024, 256);
        transpose_kernel<<<(n1+255)/256,256,0,stream>>>(whh1, wT1h, 1024, 256);
    }

    // pass A: stats (per-row blocks, all 5 windows each)
    conv1d_kernel<125,62,0,0><<<NN,256,0,stream>>>(x, w1, sclA, sftA, w13, st1, st13, y13);
    conv1d_kernel< 59,29,1,0><<<NN,256,0,stream>>>(x, w2, sclA, sftA, w13, st1, st13, y13);
    conv1d_kernel< 31,15,2,0><<<NN,256,0,stream>>>(x, w3, sclA, sftA, w13, st1, st13, y13);
    finalize_bn1<<<1,64,0,stream>>>(st1, g1, be1, g2, be2, g3, be3, sclA, sftA);
    // pass B: apply + mix
    conv1d_kernel<125,62,0,1><<<NN,256,0,stream>>>(x, w1, sclA, sftA, w13, st1, st13, y13);
    conv1d_kernel< 59,29,1,1><<<NN,256,0,stream>>>(x, w2, sclA, sftA, w13, st1, st13, y13);
    conv1d_kernel< 31,15,2,1><<<NN,256,0,stream>>>(x, w3, sclA, sftA, w13, st1, st13, y13);
    finalize_bn13<<<1,16,0,stream>>>(st13, g13, be13, sc13, sf13);

    feat_kernel<<<NROW,256,0,stream>>>(y13, sc13, sf13, feat);
    gcn_h_kernel<<<NROW/8,256,0,stream>>>(feat, gcn_w, hbuf);

    deg_kernel<<<(NE+255)/256,256,0,stream>>>(ei, edge_w, dinv);
    dinv_kernel<<<(NN+255)/256,256,0,stream>>>(dinv);
    agg_kernel<<<NE,64,0,stream>>>(ei, edge_w, dinv, hbuf, agg);
    bn2_stats_kernel<<<Bb,256,0,stream>>>(hbuf, dinv, agg, bn2s, bn2s+500);
    bn2_fin_kernel<<<2,256,0,stream>>>(bn2s, bn2s+500, bn2g, bn2b, scl2, scl2+500);

    zconv_kernel<<<NB,256,0,stream>>>(agg, scl2, scl2+500, w11, b11, seqb);

    lstm_attn_kernel<<<Bb,256,0,stream>>>(seqb, wT0i, wT0h, bih0, bhh0,
                                          wT1i, wT1h, bih1, bhh1, out);
}